// Round 2
// baseline (664.416 us; speedup 1.0000x reference)
//
#include <hip/hip_runtime.h>
#include <math.h>

#define NEGC 1e10f
#define EPSF 1e-8f

// problem sizes
#define NB 128
#define NL 48
#define NA 16
#define ND 256
#define NH 128
#define NS 47        // L-1 merge steps
#define PROWS 95     // 48 initial + 47 merged rows
#define PB_STRIDE (PROWS*ND)

// workspace float offsets
#define WS_WT   0         // wT[d][e] = w_sem[e][d]   (256x256)
#define WS_W1T  65536     // w1T[k][j] = w1[j][k]     (512x128)
#define WS_PHYS 131072    // phys rows [B][95][256]

// output float offsets (return order: features, lefts, rights, out_word, tree_idx, tree_probs, span_bounds)
#define O_FEAT  0
#define O_LEFT  1540096
#define O_RIGHT 3080192
#define O_WORD  4620288
#define O_TIDX  6193152
#define O_TP    6199168
#define O_SPAN  6205184

// ---------------- K0: weight transposes ----------------
__global__ __launch_bounds__(256) void k_transpose(const float* __restrict__ w_sem,
                                                   const float* __restrict__ w1,
                                                   float* __restrict__ ws) {
  int blk = blockIdx.x, t = threadIdx.x;
  if (blk < 256) {
    // wT[d][e] = w_sem[e][d]; d = blk, e = t
    ws[WS_WT + blk*256 + t] = w_sem[t*256 + blk];
  } else {
    // w1T[k][j] = w1[j][k]; k = blk-256 in [0,512), j = t < 128
    int k = blk - 256;
    if (t < NH) ws[WS_W1T + k*NH + t] = w1[t*512 + k];
  }
}

// ---------------- K1: sem0 = maskedmax_a(x @ w_sem^T) ----------------
// one block per (b,l); 128 threads; thread t owns output cols e0=2t, 2t+1 for all 16 a's
__global__ __launch_bounds__(128) void k_sem0(const float* __restrict__ x,
                                              const int* __restrict__ lengths,
                                              const float* __restrict__ amask,
                                              float* __restrict__ ws,
                                              float* __restrict__ out) {
  __shared__ float xs[NA*ND];
  __shared__ float pen[NA];
  int bl = blockIdx.x;
  int b = bl / NL, l = bl - b*NL;
  int t = threadIdx.x;
  const float4* xg4 = (const float4*)(x + (size_t)bl*(NA*ND));
  float4* xs4 = (float4*)xs;
#pragma unroll
  for (int r = 0; r < 8; ++r) xs4[t + 128*r] = xg4[t + 128*r];
  if (t < NA) pen[t] = -NEGC * (1.0f - amask[bl*NA + t]);
  __syncthreads();
  const float* wt = ws + WS_WT;
  int e0 = t*2;
  float acc[NA][2];
#pragma unroll
  for (int a = 0; a < NA; ++a) { acc[a][0] = 0.f; acc[a][1] = 0.f; }
  for (int d0 = 0; d0 < ND; d0 += 4) {
    float2 wv0 = *(const float2*)(wt + (d0+0)*ND + e0);
    float2 wv1 = *(const float2*)(wt + (d0+1)*ND + e0);
    float2 wv2 = *(const float2*)(wt + (d0+2)*ND + e0);
    float2 wv3 = *(const float2*)(wt + (d0+3)*ND + e0);
#pragma unroll
    for (int a = 0; a < NA; ++a) {
      float4 xa = xs4[(a*ND + d0) >> 2];   // LDS broadcast read
      acc[a][0] = fmaf(xa.x, wv0.x, acc[a][0]); acc[a][1] = fmaf(xa.x, wv0.y, acc[a][1]);
      acc[a][0] = fmaf(xa.y, wv1.x, acc[a][0]); acc[a][1] = fmaf(xa.y, wv1.y, acc[a][1]);
      acc[a][0] = fmaf(xa.z, wv2.x, acc[a][0]); acc[a][1] = fmaf(xa.z, wv2.y, acc[a][1]);
      acc[a][0] = fmaf(xa.w, wv3.x, acc[a][0]); acc[a][1] = fmaf(xa.w, wv3.y, acc[a][1]);
    }
  }
  float m0 = -INFINITY, m1 = -INFINITY;
#pragma unroll
  for (int a = 0; a < NA; ++a) {
    m0 = fmaxf(m0, acc[a][0] + pen[a]);
    m1 = fmaxf(m1, acc[a][1] + pen[a]);
  }
  float* prow = ws + WS_PHYS + (size_t)b*PB_STRIDE + l*ND;
  *(float2*)(prow + e0) = make_float2(m0, m1);
  float wm = (l < lengths[b]) ? 1.0f : 0.0f;
  *(float2*)(out + O_WORD + (size_t)bl*ND + e0) = make_float2(m0*wm, m1*wm);
}

// ---------------- K2 helper: batched logit GEMV for up to NP pair-positions ----------------
template<int NP>
__device__ __forceinline__ void compute_logits(
    int t, const int* pos, int npValid,
    const float* __restrict__ pb, const float* __restrict__ w1t,
    float* feats /* [4*512] */, float* part /* [2*4*128] */,
    const int* physIdx, const float* invn,
    const float* b1s, const float* w2s, float* logits)
{
  int lane = t & 63, wvv = t >> 6;
  // stage feats[c] = [ l2norm(row(p+1)) ; l2norm(row(p)) ]
  for (int c = 0; c < npValid; ++c) {
    int p = pos[c];
    int rA = physIdx[p+1], rB = physIdx[p];
    feats[c*512 + t]       = pb[rA*ND + t] * invn[rA];
    feats[c*512 + 256 + t] = pb[rB*ND + t] * invn[rB];
  }
  __syncthreads();
  int j = t & 127, half = t >> 7;   // half is wave-uniform
  float acc[NP];
#pragma unroll
  for (int c = 0; c < NP; ++c) acc[c] = 0.f;
  const float* wp = w1t + half*256*NH + j;
  const float* fp = feats + half*256;
#pragma unroll 8
  for (int kk = 0; kk < 256; ++kk) {
    float w = wp[kk*NH];
#pragma unroll
    for (int c = 0; c < NP; ++c) acc[c] = fmaf(w, fp[c*512 + kk], acc[c]);
  }
#pragma unroll
  for (int c = 0; c < NP; ++c) part[(half*4 + c)*NH + j] = acc[c];
  __syncthreads();
  // finalize: wave wvv handles position wvv
  if (wvv < npValid) {
    int p = pos[wvv];
    float h0 = b1s[lane]    + part[(0*4+wvv)*NH + lane]    + part[(1*4+wvv)*NH + lane];
    float h1 = b1s[lane+64] + part[(0*4+wvv)*NH + lane+64] + part[(1*4+wvv)*NH + lane+64];
    h0 = fmaxf(h0, 0.f); h1 = fmaxf(h1, 0.f);
    float v = w2s[lane]*h0 + w2s[lane+64]*h1;
#pragma unroll
    for (int off = 32; off; off >>= 1) v += __shfl_down(v, off);
    if (lane == 0) logits[p] = v;
  }
  __syncthreads();
}

// ---------------- K2: greedy merge scan, one block per batch ----------------
__global__ __launch_bounds__(256) void k_tree(const int* __restrict__ lengths,
                                              float* __restrict__ ws,
                                              const float* __restrict__ b1g,
                                              const float* __restrict__ w2g,
                                              float* __restrict__ out) {
  __shared__ float feats[4*512];
  __shared__ float part[2*4*128];
  __shared__ float logits[48];
  __shared__ int physIdx[48];
  __shared__ int lbA[48];
  __shared__ int rbA[48];
  __shared__ float invn[PROWS];
  __shared__ float b1s[NH];
  __shared__ float w2s[NH];
  __shared__ float red[8];
  __shared__ int s_idx;
  __shared__ float s_tp;

  int b = blockIdx.x;
  int t = threadIdx.x;
  int lane = t & 63, wv = t >> 6;
  float* pb = ws + WS_PHYS + (size_t)b*PB_STRIDE;
  const float* w1t = ws + WS_W1T;
  int len = lengths[b];

  if (t < NH) { b1s[t] = b1g[t]; w2s[t] = w2g[t]; }
  if (t < 48) { physIdx[t] = t; lbA[t] = t; rbA[t] = t; }
  __syncthreads();
  // initial inverse norms of rows 0..47 (wave wv does rows wv, wv+4, ...)
  for (int r = wv; r < 48; r += 4) {
    float4 v4 = ((const float4*)(pb + r*ND))[lane];
    float s = v4.x*v4.x + v4.y*v4.y + v4.z*v4.z + v4.w*v4.w;
#pragma unroll
    for (int off = 32; off; off >>= 1) s += __shfl_down(s, off);
    if (lane == 0) invn[r] = 1.0f / (sqrtf(s) + EPSF);
  }
  __syncthreads();

  int pidx = 0;
  for (int i = 0; i < NS; ++i) {
    int valid = len - 1 - i; if (valid < 0) valid = 0;
    // ---- 1. logits (only needed when valid >= 2; domain = positions 0..valid-1) ----
    if (valid >= 2) {
      if (i == 0) {
        int pos[4];
        for (int c0 = 0; c0 < valid; c0 += 4) {
          int np = valid - c0; np = np > 4 ? 4 : np;
          pos[0] = c0; pos[1] = c0+1; pos[2] = c0+2; pos[3] = c0+3;
          compute_logits<4>(t, pos, np, pb, w1t, feats, part, physIdx, invn, b1s, w2s, logits);
        }
      } else {
        // fresh positions after previous merge at pidx: {pidx-1, pidx} clipped to domain.
        // (shifted cache for positions > pidx was updated in prior bookkeeping.)
        int pos[2]; int np = 0;
        if (pidx > 0) pos[np++] = pidx - 1;
        if (pidx <= valid - 1) pos[np++] = pidx;
        compute_logits<2>(t, pos, np, pb, w1t, feats, part, physIdx, invn, b1s, w2s, logits);
      }
      // ---- 2. masked argmax (first occurrence) + softmax prob over domain ----
      if (wv == 0) {
        float v = (lane < valid) ? logits[lane] : -INFINITY;
        int bi = lane;
#pragma unroll
        for (int off = 32; off; off >>= 1) {
          float ov = __shfl_down(v, off);
          int  oi = __shfl_down(bi, off);
          if (ov > v || (ov == v && oi < bi)) { v = ov; bi = oi; }
        }
        bi = __shfl(bi, 0);
        v  = __shfl(v, 0);
        float ee = (lane < valid) ? expf(logits[lane] - v) : 0.f;
#pragma unroll
        for (int off = 32; off; off >>= 1) ee += __shfl_down(ee, off);
        if (lane == 0) { s_idx = bi; s_tp = 1.0f / ee; }
      }
    } else {
      // valid==1: single unmasked slot -> idx=0, prob=1.
      // valid==0: ALL slots masked by -1e10; fp32 absorbs logit (ulp(1e10)=1024) so all
      // masked logits are bitwise -1e10 -> softmax exactly uniform -> argmax=0, tp=1/47.
      if (t == 0) { s_idx = 0; s_tp = (valid == 1) ? 1.0f : (1.0f/47.0f); }
    }
    __syncthreads();
    int idx = s_idx;
    // ---- 3. gather rows, merged feature, outputs ----
    int rL = physIdx[idx], rR = physIdx[idx+1];
    float slv = pb[rL*ND + t];
    float srv = pb[rR*ND + t];
    float sumv = slv + srv;
    float q2 = sumv * sumv;
#pragma unroll
    for (int off = 32; off; off >>= 1) q2 += __shfl_down(q2, off);
    if (lane == 0) red[wv] = q2;
    __syncthreads();
    float invns = 1.0f / (sqrtf(red[0]+red[1]+red[2]+red[3]) + EPSF);
    float featv = sumv * invns;
    float undone = valid > 0 ? 1.0f : 0.0f;
    int ob = (i*NB + b)*ND + t;
    out[O_FEAT  + ob] = featv * undone;
    out[O_LEFT  + ob] = slv * invn[rL] * undone;
    out[O_RIGHT + ob] = srv * invn[rR] * undone;
    int rNew = 48 + i;
    pb[rNew*ND + t] = featv;
    float q3 = featv * featv;
#pragma unroll
    for (int off = 32; off; off >>= 1) q3 += __shfl_down(q3, off);
    if (lane == 0) red[4+wv] = q3;
    if (t == 0) {
      out[O_TIDX + i*NB + b] = (float)idx;
      out[O_TP   + i*NB + b] = s_tp;
      out[O_SPAN + (i*NB + b)*2 + 0] = (float)lbA[idx];
      out[O_SPAN + (i*NB + b)*2 + 1] = (float)rbA[idx+1];
    }
    __syncthreads();
    // ---- 4. merge bookkeeping (single thread; ascending in-place deletes are safe) ----
    if (t == 0) {
      invn[rNew] = 1.0f / (sqrtf(red[4]+red[5]+red[6]+red[7]) + EPSF);
      physIdx[idx] = rNew;
      for (int jj = idx+1; jj < 47; ++jj) physIdx[jj] = physIdx[jj+1];
      for (int jj = idx+1; jj < 47; ++jj) lbA[jj] = lbA[jj+1];       // lb: delete at idx+1
      rbA[idx] = rbA[idx+1];                                          // rb: delete at idx
      for (int jj = idx+1; jj < 47; ++jj) rbA[jj] = rbA[jj+1];
      for (int jj = idx+1; jj <= 45; ++jj) logits[jj] = logits[jj+1]; // logits shift
    }
    __syncthreads();
    pidx = idx;
  }
}

extern "C" void kernel_launch(void* const* d_in, const int* in_sizes, int n_in,
                              void* d_out, int out_size, void* d_ws, size_t ws_size,
                              hipStream_t stream) {
  const float* x      = (const float*)d_in[0];
  const int*   lengths= (const int*)  d_in[1];
  const float* amask  = (const float*)d_in[2];
  const float* w_sem  = (const float*)d_in[3];
  const float* w1     = (const float*)d_in[4];
  const float* b1     = (const float*)d_in[5];
  const float* w2     = (const float*)d_in[6];
  float* out = (float*)d_out;
  float* ws  = (float*)d_ws;

  k_transpose<<<dim3(768), dim3(256), 0, stream>>>(w_sem, w1, ws);
  k_sem0<<<dim3(NB*NL), dim3(128), 0, stream>>>(x, lengths, amask, ws, out);
  k_tree<<<dim3(NB), dim3(256), 0, stream>>>(lengths, ws, b1, w2, out);
}

// Round 3
// 628.014 us; speedup vs baseline: 1.0580x; 1.0580x over previous
//
#include <hip/hip_runtime.h>
#include <math.h>

#define NEGC 1e10f
#define EPSF 1e-8f

// problem sizes
#define NB 128
#define NL 48
#define NA 16
#define ND 256
#define NH 128
#define NS 47        // L-1 merge steps
#define PB_STRIDE (NL*ND)   // 48 rows per batch in global handoff buffer

// workspace float offsets
#define WS_WT   0         // wT[d][e] = w_sem[e][d]   (256x256)
#define WS_PHYS 65536     // sem0 rows [B][48][256]

// output float offsets (return order: features, lefts, rights, out_word, tree_idx, tree_probs, span_bounds)
#define O_FEAT  0
#define O_LEFT  1540096
#define O_RIGHT 3080192
#define O_WORD  4620288
#define O_TIDX  6193152
#define O_TP    6199168
#define O_SPAN  6205184

// ---------------- K0: w_sem transpose ----------------
__global__ __launch_bounds__(256) void k_transpose(const float* __restrict__ w_sem,
                                                   float* __restrict__ ws) {
  int blk = blockIdx.x, t = threadIdx.x;
  // wT[d][e] = w_sem[e][d]; d = blk, e = t
  ws[WS_WT + blk*256 + t] = w_sem[t*256 + blk];
}

// ---------------- K1: sem0 = maskedmax_a(x @ w_sem^T) ----------------
__global__ __launch_bounds__(128) void k_sem0(const float* __restrict__ x,
                                              const int* __restrict__ lengths,
                                              const float* __restrict__ amask,
                                              float* __restrict__ ws,
                                              float* __restrict__ out) {
  __shared__ float xs[NA*ND];
  __shared__ float pen[NA];
  int bl = blockIdx.x;
  int b = bl / NL, l = bl - b*NL;
  int t = threadIdx.x;
  const float4* xg4 = (const float4*)(x + (size_t)bl*(NA*ND));
  float4* xs4 = (float4*)xs;
#pragma unroll
  for (int r = 0; r < 8; ++r) xs4[t + 128*r] = xg4[t + 128*r];
  if (t < NA) pen[t] = -NEGC * (1.0f - amask[bl*NA + t]);
  __syncthreads();
  const float* wt = ws + WS_WT;
  int e0 = t*2;
  float acc[NA][2];
#pragma unroll
  for (int a = 0; a < NA; ++a) { acc[a][0] = 0.f; acc[a][1] = 0.f; }
  for (int d0 = 0; d0 < ND; d0 += 4) {
    float2 wv0 = *(const float2*)(wt + (d0+0)*ND + e0);
    float2 wv1 = *(const float2*)(wt + (d0+1)*ND + e0);
    float2 wv2 = *(const float2*)(wt + (d0+2)*ND + e0);
    float2 wv3 = *(const float2*)(wt + (d0+3)*ND + e0);
#pragma unroll
    for (int a = 0; a < NA; ++a) {
      float4 xa = xs4[(a*ND + d0) >> 2];   // LDS broadcast read
      acc[a][0] = fmaf(xa.x, wv0.x, acc[a][0]); acc[a][1] = fmaf(xa.x, wv0.y, acc[a][1]);
      acc[a][0] = fmaf(xa.y, wv1.x, acc[a][0]); acc[a][1] = fmaf(xa.y, wv1.y, acc[a][1]);
      acc[a][0] = fmaf(xa.z, wv2.x, acc[a][0]); acc[a][1] = fmaf(xa.z, wv2.y, acc[a][1]);
      acc[a][0] = fmaf(xa.w, wv3.x, acc[a][0]); acc[a][1] = fmaf(xa.w, wv3.y, acc[a][1]);
    }
  }
  float m0 = -INFINITY, m1 = -INFINITY;
#pragma unroll
  for (int a = 0; a < NA; ++a) {
    m0 = fmaxf(m0, acc[a][0] + pen[a]);
    m1 = fmaxf(m1, acc[a][1] + pen[a]);
  }
  float* prow = ws + WS_PHYS + (size_t)b*PB_STRIDE + l*ND;
  *(float2*)(prow + e0) = make_float2(m0, m1);
  float wm = (l < lengths[b]) ? 1.0f : 0.0f;
  *(float2*)(out + O_WORD + (size_t)bl*ND + e0) = make_float2(m0*wm, m1*wm);
}

// ---------------- K2 helper: batched logit GEMV from register-resident w1 ----------------
// rows[48][256] live in LDS; w1 slice lives in each thread's registers.
template<int NPmax>
__device__ __forceinline__ void compute_logits_reg(
    int t, const int* pos, int npValid,
    const float4 (&w1r4)[64],
    const float* rows, float* part,
    const int* physIdx, const float* invn,
    const float* b1s, const float* w2s, float* logits)
{
  int lane = t & 63, wvv = t >> 6;
  int j = t & 127, half = t >> 7;      // wave-uniform half
#pragma unroll
  for (int c = 0; c < NPmax; ++c) {
    if (c < npValid) {
      int p = pos[c];
      int r = (half == 0) ? physIdx[p+1] : physIdx[p];   // half0: right row, half1: left row
      const float4* rp = (const float4*)(rows + r*ND);
      float inr = invn[r];
      float4 a = make_float4(0.f, 0.f, 0.f, 0.f);
#pragma unroll
      for (int kk = 0; kk < 64; ++kk) {
        float4 rv = rp[kk];              // LDS broadcast (uniform addr per wave)
        float fx = rv.x*inr, fy = rv.y*inr, fz = rv.z*inr, fw = rv.w*inr;  // rounded feats
        a.x = fmaf(w1r4[kk].x, fx, a.x);
        a.y = fmaf(w1r4[kk].y, fy, a.y);
        a.z = fmaf(w1r4[kk].z, fz, a.z);
        a.w = fmaf(w1r4[kk].w, fw, a.w);
      }
      part[(half*4 + c)*NH + j] = (a.x + a.y) + (a.z + a.w);
    }
  }
  __syncthreads();
  if (wvv < npValid) {
    int p = pos[wvv];
    float h0 = b1s[lane]    + part[(0*4+wvv)*NH + lane]    + part[(1*4+wvv)*NH + lane];
    float h1 = b1s[lane+64] + part[(0*4+wvv)*NH + lane+64] + part[(1*4+wvv)*NH + lane+64];
    h0 = fmaxf(h0, 0.f); h1 = fmaxf(h1, 0.f);
    float v = w2s[lane]*h0 + w2s[lane+64]*h1;
#pragma unroll
    for (int off = 32; off; off >>= 1) v += __shfl_down(v, off);
    if (lane == 0) logits[p] = v;
  }
  __syncthreads();
}

// ---------------- K2: greedy merge scan, one block per batch ----------------
__global__ __launch_bounds__(256, 1) void k_tree(const int* __restrict__ lengths,
                                                 const float* __restrict__ ws,
                                                 const float* __restrict__ w1g,
                                                 const float* __restrict__ b1g,
                                                 const float* __restrict__ w2g,
                                                 float* __restrict__ out) {
  __shared__ float rows[NL*ND];      // 48 KB: physical row slots (merged row reuses left slot)
  __shared__ float part[2*4*NH];
  __shared__ float logits[48];
  __shared__ int physIdx[48];
  __shared__ int lbA[48];
  __shared__ int rbA[48];
  __shared__ float invn[48];
  __shared__ float b1s[NH];
  __shared__ float w2s[NH];
  __shared__ float red[8];
  __shared__ int s_idx;
  __shared__ float s_tp;

  int b = blockIdx.x;
  int t = threadIdx.x;
  int lane = t & 63, wv = t >> 6;
  int j = t & 127, half = t >> 7;
  int len = lengths[b];

  // w1 slice into registers: w1[j][half*256 .. +256) = 64 contiguous float4
  float4 w1r4[64];
  {
    const float4* wsrc = (const float4*)(w1g + j*512 + half*256);
#pragma unroll
    for (int kk = 0; kk < 64; ++kk) w1r4[kk] = wsrc[kk];
  }

  if (t < NH) { b1s[t] = b1g[t]; w2s[t] = w2g[t]; }
  if (t < 48) { physIdx[t] = t; lbA[t] = t; rbA[t] = t; }
  // stage sem0 rows into LDS (wave wv loads rows wv, wv+4, ...)
  {
    const float4* pg = (const float4*)(ws + WS_PHYS + (size_t)b*PB_STRIDE);
    float4* rows4 = (float4*)rows;
    for (int r = wv; r < NL; r += 4) rows4[r*64 + lane] = pg[r*64 + lane];
  }
  __syncthreads();
  // initial inverse norms
  for (int r = wv; r < NL; r += 4) {
    float4 v4 = ((const float4*)(rows + r*ND))[lane];
    float s = v4.x*v4.x + v4.y*v4.y + v4.z*v4.z + v4.w*v4.w;
#pragma unroll
    for (int off = 32; off; off >>= 1) s += __shfl_down(s, off);
    if (lane == 0) invn[r] = 1.0f / (sqrtf(s) + EPSF);
  }
  __syncthreads();

  int pidx = 0;
  for (int i = 0; i < NS; ++i) {
    int valid = len - 1 - i; if (valid < 0) valid = 0;
    // ---- 1. logits (only when valid >= 2; domain = 0..valid-1) ----
    if (valid >= 2) {
      if (i == 0) {
        int pos[4];
        for (int c0 = 0; c0 < valid; c0 += 4) {
          int np = valid - c0; np = np > 4 ? 4 : np;
          pos[0] = c0; pos[1] = c0+1; pos[2] = c0+2; pos[3] = c0+3;
          compute_logits_reg<4>(t, pos, np, w1r4, rows, part, physIdx, invn, b1s, w2s, logits);
        }
      } else {
        int pos[2]; int np = 0;
        if (pidx > 0) pos[np++] = pidx - 1;
        if (pidx <= valid - 1) pos[np++] = pidx;
        pos[1] = (np > 1) ? pos[1] : pos[0];
        compute_logits_reg<2>(t, pos, np, w1r4, rows, part, physIdx, invn, b1s, w2s, logits);
      }
      // ---- 2. masked argmax (first occurrence) + softmax prob over domain ----
      if (wv == 0) {
        float v = (lane < valid) ? logits[lane] : -INFINITY;
        int bi = lane;
#pragma unroll
        for (int off = 32; off; off >>= 1) {
          float ov = __shfl_down(v, off);
          int  oi = __shfl_down(bi, off);
          if (ov > v || (ov == v && oi < bi)) { v = ov; bi = oi; }
        }
        bi = __shfl(bi, 0);
        v  = __shfl(v, 0);
        float ee = (lane < valid) ? expf(logits[lane] - v) : 0.f;
#pragma unroll
        for (int off = 32; off; off >>= 1) ee += __shfl_down(ee, off);
        if (lane == 0) { s_idx = bi; s_tp = 1.0f / ee; }
      }
    } else {
      // valid==1: single unmasked slot -> idx=0, prob=1.
      // valid==0: all logits bitwise -1e10 (fp32 absorption) -> uniform softmax: idx=0, tp=1/47.
      if (t == 0) { s_idx = 0; s_tp = (valid == 1) ? 1.0f : (1.0f/47.0f); }
    }
    __syncthreads();
    int idx = s_idx;
    // ---- 3. merge: gather, reduce, outputs, in-place row update, parallel shifts ----
    int rL = physIdx[idx], rR = physIdx[idx+1];
    float slv = rows[rL*ND + t];
    float srv = rows[rR*ND + t];
    float inL = invn[rL], inR = invn[rR];
    float sumv = slv + srv;
    float q2 = sumv * sumv;
#pragma unroll
    for (int off = 32; off; off >>= 1) q2 += __shfl_down(q2, off);
    if (lane == 0) red[wv] = q2;
    // read shift sources before any writes
    int pv = 0, lv = 0, rv_ = 0; float gv = 0.f;
    if (t < 47) { pv = physIdx[t+1]; lv = lbA[t+1]; rv_ = rbA[t+1]; gv = logits[t+1]; }
    int sp0 = lbA[idx], sp1 = rbA[idx+1];
    __syncthreads();
    float invns = 1.0f / (sqrtf(red[0]+red[1]+red[2]+red[3]) + EPSF);
    float featv = sumv * invns;
    float undone = valid > 0 ? 1.0f : 0.0f;
    int ob = (i*NB + b)*ND + t;
    out[O_FEAT  + ob] = featv * undone;
    out[O_LEFT  + ob] = slv * inL * undone;
    out[O_RIGHT + ob] = srv * inR * undone;
    rows[rL*ND + t] = featv;           // merged row reuses left child's slot
    float q3 = featv * featv;
#pragma unroll
    for (int off = 32; off; off >>= 1) q3 += __shfl_down(q3, off);
    if (lane == 0) red[4+wv] = q3;
    if (t == 0) {
      out[O_TIDX + i*NB + b] = (float)idx;
      out[O_TP   + i*NB + b] = s_tp;
      out[O_SPAN + (i*NB + b)*2 + 0] = (float)sp0;
      out[O_SPAN + (i*NB + b)*2 + 1] = (float)sp1;
    }
    // parallel deletes: phys/lb/logits delete at idx+1, rb delete at idx
    if (t > idx && t < 47) { physIdx[t] = pv; lbA[t] = lv; logits[t] = gv; }
    if (t >= idx && t < 47) rbA[t] = rv_;
    __syncthreads();
    if (t == 0) invn[rL] = 1.0f / (sqrtf(red[4]+red[5]+red[6]+red[7]) + EPSF);
    __syncthreads();
    pidx = idx;
  }
}

extern "C" void kernel_launch(void* const* d_in, const int* in_sizes, int n_in,
                              void* d_out, int out_size, void* d_ws, size_t ws_size,
                              hipStream_t stream) {
  const float* x      = (const float*)d_in[0];
  const int*   lengths= (const int*)  d_in[1];
  const float* amask  = (const float*)d_in[2];
  const float* w_sem  = (const float*)d_in[3];
  const float* w1     = (const float*)d_in[4];
  const float* b1     = (const float*)d_in[5];
  const float* w2     = (const float*)d_in[6];
  float* out = (float*)d_out;
  float* ws  = (float*)d_ws;

  k_transpose<<<dim3(256), dim3(256), 0, stream>>>(w_sem, ws);
  k_sem0<<<dim3(NB*NL), dim3(128), 0, stream>>>(x, lengths, amask, ws, out);
  k_tree<<<dim3(NB), dim3(256), 0, stream>>>(lengths, ws, w1, b1, w2, out);
}

// Round 4
// 419.010 us; speedup vs baseline: 1.5857x; 1.4988x over previous
//
#include <hip/hip_runtime.h>
#include <math.h>

#define NEGC 1e10f
#define EPSF 1e-8f

// problem sizes
#define NB 128
#define NL 48
#define NA 16
#define ND 256
#define NH 128
#define NS 47
#define PB_STRIDE (NL*ND)

// ws float offsets
#define WS_WT   0                 // wT[d][e] = w_sem[e][d] (256x256)
#define WS_INVN 65536             // [B][48] initial inverse norms
#define WS_LOG  (65536+6144)      // [B][48] initial logits
#define WS_PHYS (65536+12288)     // [B][48][256] sem0 rows

// out float offsets (features, lefts, rights, out_word, tree_idx, tree_probs, span_bounds)
#define O_FEAT  0
#define O_LEFT  1540096
#define O_RIGHT 3080192
#define O_WORD  4620288
#define O_TIDX  6193152
#define O_TP    6199168
#define O_SPAN  6205184

// ---------------- K0: w_sem transpose ----------------
__global__ __launch_bounds__(256) void k_transpose(const float* __restrict__ w_sem,
                                                   float* __restrict__ ws) {
  int blk = blockIdx.x, t = threadIdx.x;
  ws[WS_WT + blk*256 + t] = w_sem[t*256 + blk];
}

// ---------------- K1: sem0 = maskedmax_a(x @ w_sem^T), + row inverse norms ----------------
__global__ __launch_bounds__(128) void k_sem0(const float* __restrict__ x,
                                              const int* __restrict__ lengths,
                                              const float* __restrict__ amask,
                                              float* __restrict__ ws,
                                              float* __restrict__ out) {
  __shared__ float xs[NA*ND];
  __shared__ float pen[NA];
  __shared__ float red2[2];
  int bl = blockIdx.x;
  int b = bl / NL, l = bl - b*NL;
  int t = threadIdx.x;
  const float4* xg4 = (const float4*)(x + (size_t)bl*(NA*ND));
  float4* xs4 = (float4*)xs;
#pragma unroll
  for (int r = 0; r < 8; ++r) xs4[t + 128*r] = xg4[t + 128*r];
  if (t < NA) pen[t] = -NEGC * (1.0f - amask[bl*NA + t]);
  __syncthreads();
  const float* wt = ws + WS_WT;
  int e0 = t*2;
  float acc[NA][2];
#pragma unroll
  for (int a = 0; a < NA; ++a) { acc[a][0] = 0.f; acc[a][1] = 0.f; }
  for (int d0 = 0; d0 < ND; d0 += 4) {
    float2 wv0 = *(const float2*)(wt + (d0+0)*ND + e0);
    float2 wv1 = *(const float2*)(wt + (d0+1)*ND + e0);
    float2 wv2 = *(const float2*)(wt + (d0+2)*ND + e0);
    float2 wv3 = *(const float2*)(wt + (d0+3)*ND + e0);
#pragma unroll
    for (int a = 0; a < NA; ++a) {
      float4 xa = xs4[(a*ND + d0) >> 2];
      acc[a][0] = fmaf(xa.x, wv0.x, acc[a][0]); acc[a][1] = fmaf(xa.x, wv0.y, acc[a][1]);
      acc[a][0] = fmaf(xa.y, wv1.x, acc[a][0]); acc[a][1] = fmaf(xa.y, wv1.y, acc[a][1]);
      acc[a][0] = fmaf(xa.z, wv2.x, acc[a][0]); acc[a][1] = fmaf(xa.z, wv2.y, acc[a][1]);
      acc[a][0] = fmaf(xa.w, wv3.x, acc[a][0]); acc[a][1] = fmaf(xa.w, wv3.y, acc[a][1]);
    }
  }
  float m0 = -INFINITY, m1 = -INFINITY;
#pragma unroll
  for (int a = 0; a < NA; ++a) {
    m0 = fmaxf(m0, acc[a][0] + pen[a]);
    m1 = fmaxf(m1, acc[a][1] + pen[a]);
  }
  float* prow = ws + WS_PHYS + (size_t)b*PB_STRIDE + l*ND;
  *(float2*)(prow + e0) = make_float2(m0, m1);
  float wm = (l < lengths[b]) ? 1.0f : 0.0f;
  *(float2*)(out + O_WORD + (size_t)bl*ND + e0) = make_float2(m0*wm, m1*wm);
  // row inverse norm: reduce m0^2+m1^2 over 128 threads (2 waves)
  float s2 = m0*m0 + m1*m1;
#pragma unroll
  for (int off = 32; off; off >>= 1) s2 += __shfl_down(s2, off);
  if ((t & 63) == 0) red2[t >> 6] = s2;
  __syncthreads();
  if (t == 0) ws[WS_INVN + bl] = 1.0f / (sqrtf(red2[0] + red2[1]) + EPSF);
}

// ---------------- K2: initial logits for all 47 positions, full-GPU parallel ----------------
// grid 256: b = bid>>1, h = bid&1; positions p in [h*24, h*24+ (h?23:24))
__global__ __launch_bounds__(512, 1) void k_prelogits(float* __restrict__ ws,
                                                      const float* __restrict__ w1g,
                                                      const float* __restrict__ b1g,
                                                      const float* __restrict__ w2g) {
  __shared__ float rows[25*ND];      // 25 KB
  __shared__ float part[4*8*NH];     // 16 KB
  __shared__ float invl[25];
  __shared__ float b1s[NH];
  __shared__ float w2s[NH];
  int bid = blockIdx.x;
  int b = bid >> 1, h = bid & 1;
  int p0 = h*24;
  int np = h ? 23 : 24;
  int nrows = h ? 24 : 25;
  int t = threadIdx.x;
  int lane = t & 63, wv = t >> 6;
  int j = t & 127, q = t >> 7;

  // w1 slice into registers: 32 float4 = 128 VGPR
  float4 w1r[32];
  {
    const float4* wsrc = (const float4*)(w1g + (size_t)j*512 + q*128);
#pragma unroll
    for (int kk = 0; kk < 32; ++kk) w1r[kk] = wsrc[kk];
  }
  if (t < NH) { b1s[t] = b1g[t]; w2s[t] = w2g[t]; }
  if (t < nrows) invl[t] = ws[WS_INVN + b*48 + p0 + t];
  {
    const float4* pg4 = (const float4*)(ws + WS_PHYS + (size_t)b*PB_STRIDE);
    float4* rows4 = (float4*)rows;
    int n4 = nrows * 64;
    for (int u = t; u < n4; u += 512) rows4[u] = pg4[p0*64 + u];
  }
  __syncthreads();

  for (int ct = 0; ct < 3; ++ct) {
#pragma unroll
    for (int c = 0; c < 8; ++c) {
      int pp = ct*8 + c;
      if (pp < np) {
        int rloc = (q < 2) ? pp + 1 : pp;     // q 0,1: right row; q 2,3: left row
        const float4* rp4 = (const float4*)(rows + rloc*ND + (q & 1)*128);
        float4 a = make_float4(0.f, 0.f, 0.f, 0.f);
#pragma unroll
        for (int kk = 0; kk < 32; ++kk) {
          float4 rv = rp4[kk];
          a.x = fmaf(w1r[kk].x, rv.x, a.x);
          a.y = fmaf(w1r[kk].y, rv.y, a.y);
          a.z = fmaf(w1r[kk].z, rv.z, a.z);
          a.w = fmaf(w1r[kk].w, rv.w, a.w);
        }
        part[(q*8 + c)*NH + j] = (a.x + a.y) + (a.z + a.w);
      }
    }
    __syncthreads();
    int pp = ct*8 + wv;
    if (pp < np) {
      float inR = invl[pp + 1], inL = invl[pp];
      float pr0 = part[(0*8+wv)*NH + lane]      + part[(1*8+wv)*NH + lane];
      float pl0 = part[(2*8+wv)*NH + lane]      + part[(3*8+wv)*NH + lane];
      float pr1 = part[(0*8+wv)*NH + lane + 64] + part[(1*8+wv)*NH + lane + 64];
      float pl1 = part[(2*8+wv)*NH + lane + 64] + part[(3*8+wv)*NH + lane + 64];
      float h0 = fmaf(inR, pr0, fmaf(inL, pl0, b1s[lane]));
      float h1 = fmaf(inR, pr1, fmaf(inL, pl1, b1s[lane + 64]));
      h0 = fmaxf(h0, 0.f); h1 = fmaxf(h1, 0.f);
      float v = w2s[lane]*h0 + w2s[lane + 64]*h1;
#pragma unroll
      for (int off = 32; off; off >>= 1) v += __shfl_down(v, off);
      if (lane == 0) ws[WS_LOG + b*48 + p0 + pp] = v;
    }
    __syncthreads();
  }
}

// ---------------- K3: greedy merge scan, one block per batch, 512 threads ----------------
__global__ __launch_bounds__(512, 1) void k_tree(const int* __restrict__ lengths,
                                                 float* __restrict__ ws,
                                                 const float* __restrict__ w1g,
                                                 const float* __restrict__ b1g,
                                                 const float* __restrict__ w2g,
                                                 float* __restrict__ out) {
  __shared__ float rows[NL*ND];      // 48 KB, slot-reuse on merge
  __shared__ float part[4*2*NH];     // 4 KB
  __shared__ float logits[48];
  __shared__ int physIdx[48];
  __shared__ int lbA[48];
  __shared__ int rbA[48];
  __shared__ float invn[48];
  __shared__ float b1s[NH];
  __shared__ float w2s[NH];
  __shared__ float red[8];
  __shared__ int s_idx;
  __shared__ float s_tp;

  int b = blockIdx.x;
  int t = threadIdx.x;
  int lane = t & 63, wv = t >> 6;
  int j = t & 127, q = t >> 7;
  int len = lengths[b];

  // w1 slice into registers: 32 float4 = 128 VGPR (q-split of k-range)
  float4 w1r[32];
  {
    const float4* wsrc = (const float4*)(w1g + (size_t)j*512 + q*128);
#pragma unroll
    for (int kk = 0; kk < 32; ++kk) w1r[kk] = wsrc[kk];
  }

  if (t < NH) { b1s[t] = b1g[t]; w2s[t] = w2g[t]; }
  if (t < 48) { physIdx[t] = t; lbA[t] = t; rbA[t] = t; invn[t] = ws[WS_INVN + b*48 + t]; }
  if (t < 47) logits[t] = ws[WS_LOG + b*48 + t];
  {
    const float4* pg4 = (const float4*)(ws + WS_PHYS + (size_t)b*PB_STRIDE);
    float4* rows4 = (float4*)rows;
    for (int u = t; u < NL*64; u += 512) rows4[u] = pg4[u];
  }
  __syncthreads();

  int pidx = -1;
  for (int i = 0; i < NS; ++i) {
    int valid = len - 1 - i; if (valid < 0) valid = 0;
    if (valid >= 2) {
      if (i > 0) {
        // fresh logits for {pidx-1, pidx} clipped to domain
        int pos[2]; int np = 0;
        if (pidx > 0) pos[np++] = pidx - 1;
        if (pidx <= valid - 1) pos[np++] = pidx;
        if (np == 1) pos[1] = pos[0];
#pragma unroll
        for (int c = 0; c < 2; ++c) {
          if (c < np) {
            int p = pos[c];
            int r = (q < 2) ? physIdx[p + 1] : physIdx[p];
            const float4* rp4 = (const float4*)(rows + r*ND + (q & 1)*128);
            float4 a = make_float4(0.f, 0.f, 0.f, 0.f);
#pragma unroll
            for (int kk = 0; kk < 32; ++kk) {
              float4 rv = rp4[kk];
              a.x = fmaf(w1r[kk].x, rv.x, a.x);
              a.y = fmaf(w1r[kk].y, rv.y, a.y);
              a.z = fmaf(w1r[kk].z, rv.z, a.z);
              a.w = fmaf(w1r[kk].w, rv.w, a.w);
            }
            part[(q*2 + c)*NH + j] = (a.x + a.y) + (a.z + a.w);
          }
        }
        __syncthreads();
        if (wv < np) {
          int p = pos[wv];
          int rR = physIdx[p + 1], rLL = physIdx[p];
          float inR = invn[rR], inL = invn[rLL];
          float pr0 = part[(0*2+wv)*NH + lane]      + part[(1*2+wv)*NH + lane];
          float pl0 = part[(2*2+wv)*NH + lane]      + part[(3*2+wv)*NH + lane];
          float pr1 = part[(0*2+wv)*NH + lane + 64] + part[(1*2+wv)*NH + lane + 64];
          float pl1 = part[(2*2+wv)*NH + lane + 64] + part[(3*2+wv)*NH + lane + 64];
          float h0 = fmaf(inR, pr0, fmaf(inL, pl0, b1s[lane]));
          float h1 = fmaf(inR, pr1, fmaf(inL, pl1, b1s[lane + 64]));
          h0 = fmaxf(h0, 0.f); h1 = fmaxf(h1, 0.f);
          float v = w2s[lane]*h0 + w2s[lane + 64]*h1;
#pragma unroll
          for (int off = 32; off; off >>= 1) v += __shfl_down(v, off);
          if (lane == 0) logits[p] = v;
        }
        __syncthreads();
      }
      // masked argmax (first occurrence) + softmax prob over domain
      if (wv == 0) {
        float v = (lane < valid) ? logits[lane] : -INFINITY;
        int bi = lane;
#pragma unroll
        for (int off = 32; off; off >>= 1) {
          float ov = __shfl_down(v, off);
          int  oi = __shfl_down(bi, off);
          if (ov > v || (ov == v && oi < bi)) { v = ov; bi = oi; }
        }
        bi = __shfl(bi, 0);
        v  = __shfl(v, 0);
        float ee = (lane < valid) ? expf(logits[lane] - v) : 0.f;
#pragma unroll
        for (int off = 32; off; off >>= 1) ee += __shfl_down(ee, off);
        if (lane == 0) { s_idx = bi; s_tp = 1.0f / ee; }
      }
    } else {
      // valid==1: idx=0, tp=1. valid==0: all logits bitwise -1e10 -> uniform: idx=0, tp=1/47.
      if (t == 0) { s_idx = 0; s_tp = (valid == 1) ? 1.0f : (1.0f/47.0f); }
    }
    __syncthreads();
    int idx = s_idx;
    // ---- merge phase (threads 0..255 own row elements) ----
    int rL = physIdx[idx], rR = physIdx[idx + 1];
    float slv = 0.f, srv = 0.f, inL = 0.f, inR = 0.f, sumv = 0.f;
    if (t < ND) {
      slv = rows[rL*ND + t];
      srv = rows[rR*ND + t];
      inL = invn[rL]; inR = invn[rR];
      sumv = slv + srv;
      float q2 = sumv * sumv;
#pragma unroll
      for (int off = 32; off; off >>= 1) q2 += __shfl_down(q2, off);
      if (lane == 0) red[wv] = q2;
    }
    // pre-read shift sources before writes
    int pv = 0, lv = 0, rv_ = 0; float gv = 0.f;
    if (t < 47) { pv = physIdx[t+1]; lv = lbA[t+1]; rv_ = rbA[t+1]; gv = logits[t+1]; }
    int sp0 = lbA[idx], sp1 = rbA[idx+1];
    __syncthreads();
    float undone = valid > 0 ? 1.0f : 0.0f;
    if (t < ND) {
      float invns = 1.0f / (sqrtf(red[0]+red[1]+red[2]+red[3]) + EPSF);
      float featv = sumv * invns;
      int ob = (i*NB + b)*ND + t;
      out[O_FEAT  + ob] = featv * undone;
      out[O_LEFT  + ob] = slv * inL * undone;
      out[O_RIGHT + ob] = srv * inR * undone;
      rows[rL*ND + t] = featv;   // merged row reuses left child's slot
      float q3 = featv * featv;
#pragma unroll
      for (int off = 32; off; off >>= 1) q3 += __shfl_down(q3, off);
      if (lane == 0) red[4 + wv] = q3;
    }
    if (t == 0) {
      out[O_TIDX + i*NB + b] = (float)idx;
      out[O_TP   + i*NB + b] = s_tp;
      out[O_SPAN + (i*NB + b)*2 + 0] = (float)sp0;
      out[O_SPAN + (i*NB + b)*2 + 1] = (float)sp1;
    }
    // parallel deletes: phys/lb/logits delete at idx+1, rb delete at idx
    if (t > idx && t < 47) { physIdx[t] = pv; lbA[t] = lv; logits[t] = gv; }
    if (t >= idx && t < 47) rbA[t] = rv_;
    __syncthreads();
    if (t == 0) invn[rL] = 1.0f / (sqrtf(red[4]+red[5]+red[6]+red[7]) + EPSF);
    __syncthreads();
    pidx = idx;
  }
}

extern "C" void kernel_launch(void* const* d_in, const int* in_sizes, int n_in,
                              void* d_out, int out_size, void* d_ws, size_t ws_size,
                              hipStream_t stream) {
  const float* x      = (const float*)d_in[0];
  const int*   lengths= (const int*)  d_in[1];
  const float* amask  = (const float*)d_in[2];
  const float* w_sem  = (const float*)d_in[3];
  const float* w1     = (const float*)d_in[4];
  const float* b1     = (const float*)d_in[5];
  const float* w2     = (const float*)d_in[6];
  float* out = (float*)d_out;
  float* ws  = (float*)d_ws;

  k_transpose<<<dim3(256), dim3(256), 0, stream>>>(w_sem, ws);
  k_sem0<<<dim3(NB*NL), dim3(128), 0, stream>>>(x, lengths, amask, ws, out);
  k_prelogits<<<dim3(256), dim3(512), 0, stream>>>(ws, w1, b1, w2);
  k_tree<<<dim3(NB), dim3(512), 0, stream>>>(lengths, ws, w1, b1, w2, out);
}

// Round 5
// 374.485 us; speedup vs baseline: 1.7742x; 1.1189x over previous
//
#include <hip/hip_runtime.h>
#include <math.h>

#define NEGC 1e10f
#define EPSF 1e-8f

// problem sizes
#define NB 128
#define NL 48
#define NA 16
#define ND 256
#define NH 128
#define NS 47
#define PB_STRIDE (NL*ND)

// ws float offsets
#define WS_WT   0                 // wT[d][e] = w_sem[e][d] (256x256)
#define WS_INVN 65536             // [B][48] initial inverse norms
#define WS_LOG  (65536+6144)      // [B][48] initial logits
#define WS_PHYS (65536+12288)     // [B][48][256] sem0 rows

// out float offsets (features, lefts, rights, out_word, tree_idx, tree_probs, span_bounds)
#define O_FEAT  0
#define O_LEFT  1540096
#define O_RIGHT 3080192
#define O_WORD  4620288
#define O_TIDX  6193152
#define O_TP    6199168
#define O_SPAN  6205184

// ---------------- K0: w_sem transpose ----------------
__global__ __launch_bounds__(256) void k_transpose(const float* __restrict__ w_sem,
                                                   float* __restrict__ ws) {
  int blk = blockIdx.x, t = threadIdx.x;
  ws[WS_WT + blk*256 + t] = w_sem[t*256 + blk];
}

// ---------------- K1: sem0 = maskedmax_a(x @ w_sem^T), + row inverse norms ----------------
__global__ __launch_bounds__(128) void k_sem0(const float* __restrict__ x,
                                              const int* __restrict__ lengths,
                                              const float* __restrict__ amask,
                                              float* __restrict__ ws,
                                              float* __restrict__ out) {
  __shared__ float xs[NA*ND];
  __shared__ float pen[NA];
  __shared__ float red2[2];
  int bl = blockIdx.x;
  int b = bl / NL, l = bl - b*NL;
  int t = threadIdx.x;
  const float4* xg4 = (const float4*)(x + (size_t)bl*(NA*ND));
  float4* xs4 = (float4*)xs;
#pragma unroll
  for (int r = 0; r < 8; ++r) xs4[t + 128*r] = xg4[t + 128*r];
  if (t < NA) pen[t] = -NEGC * (1.0f - amask[bl*NA + t]);
  __syncthreads();
  const float* wt = ws + WS_WT;
  int e0 = t*2;
  float acc[NA][2];
#pragma unroll
  for (int a = 0; a < NA; ++a) { acc[a][0] = 0.f; acc[a][1] = 0.f; }
  for (int d0 = 0; d0 < ND; d0 += 4) {
    float2 wv0 = *(const float2*)(wt + (d0+0)*ND + e0);
    float2 wv1 = *(const float2*)(wt + (d0+1)*ND + e0);
    float2 wv2 = *(const float2*)(wt + (d0+2)*ND + e0);
    float2 wv3 = *(const float2*)(wt + (d0+3)*ND + e0);
#pragma unroll
    for (int a = 0; a < NA; ++a) {
      float4 xa = xs4[(a*ND + d0) >> 2];
      acc[a][0] = fmaf(xa.x, wv0.x, acc[a][0]); acc[a][1] = fmaf(xa.x, wv0.y, acc[a][1]);
      acc[a][0] = fmaf(xa.y, wv1.x, acc[a][0]); acc[a][1] = fmaf(xa.y, wv1.y, acc[a][1]);
      acc[a][0] = fmaf(xa.z, wv2.x, acc[a][0]); acc[a][1] = fmaf(xa.z, wv2.y, acc[a][1]);
      acc[a][0] = fmaf(xa.w, wv3.x, acc[a][0]); acc[a][1] = fmaf(xa.w, wv3.y, acc[a][1]);
    }
  }
  float m0 = -INFINITY, m1 = -INFINITY;
#pragma unroll
  for (int a = 0; a < NA; ++a) {
    m0 = fmaxf(m0, acc[a][0] + pen[a]);
    m1 = fmaxf(m1, acc[a][1] + pen[a]);
  }
  float* prow = ws + WS_PHYS + (size_t)b*PB_STRIDE + l*ND;
  *(float2*)(prow + e0) = make_float2(m0, m1);
  float wm = (l < lengths[b]) ? 1.0f : 0.0f;
  *(float2*)(out + O_WORD + (size_t)bl*ND + e0) = make_float2(m0*wm, m1*wm);
  float s2 = m0*m0 + m1*m1;
#pragma unroll
  for (int off = 32; off; off >>= 1) s2 += __shfl_down(s2, off);
  if ((t & 63) == 0) red2[t >> 6] = s2;
  __syncthreads();
  if (t == 0) ws[WS_INVN + bl] = 1.0f / (sqrtf(red2[0] + red2[1]) + EPSF);
}

// ---------------- K2: initial logits for all 47 positions, full-GPU parallel ----------------
__global__ __launch_bounds__(512, 1) void k_prelogits(float* __restrict__ ws,
                                                      const float* __restrict__ w1g,
                                                      const float* __restrict__ b1g,
                                                      const float* __restrict__ w2g) {
  __shared__ float rows[25*ND];
  __shared__ float part[4*8*NH];
  __shared__ float invl[25];
  __shared__ float b1s[NH];
  __shared__ float w2s[NH];
  int bid = blockIdx.x;
  int b = bid >> 1, h = bid & 1;
  int p0 = h*24;
  int np = h ? 23 : 24;
  int nrows = h ? 24 : 25;
  int t = threadIdx.x;
  int lane = t & 63, wv = t >> 6;
  int j = t & 127, q = t >> 7;

  // w1 slice pinned in registers (opaque to the optimizer -> cannot be re-loaded)
  float w1f[128];
  {
    const float4* wsrc = (const float4*)(w1g + (size_t)j*512 + q*128);
#pragma unroll
    for (int kk = 0; kk < 32; ++kk) {
      float4 v = wsrc[kk];
      w1f[4*kk+0] = v.x; w1f[4*kk+1] = v.y; w1f[4*kk+2] = v.z; w1f[4*kk+3] = v.w;
    }
  }
#pragma unroll
  for (int kk = 0; kk < 32; ++kk)
    asm volatile("" : "+v"(w1f[4*kk+0]), "+v"(w1f[4*kk+1]), "+v"(w1f[4*kk+2]), "+v"(w1f[4*kk+3]));

  if (t < NH) { b1s[t] = b1g[t]; w2s[t] = w2g[t]; }
  if (t < nrows) invl[t] = ws[WS_INVN + b*48 + p0 + t];
  {
    const float4* pg4 = (const float4*)(ws + WS_PHYS + (size_t)b*PB_STRIDE);
    float4* rows4 = (float4*)rows;
    int n4 = nrows * 64;
    for (int u = t; u < n4; u += 512) rows4[u] = pg4[p0*64 + u];
  }
  __syncthreads();

  for (int ct = 0; ct < 3; ++ct) {
#pragma unroll
    for (int c = 0; c < 8; ++c) {
      int pp = ct*8 + c;
      if (pp < np) {
        int rloc = (q < 2) ? pp + 1 : pp;
        const float4* rp4 = (const float4*)(rows + rloc*ND + (q & 1)*128);
        float ax = 0.f, ay = 0.f, az = 0.f, aw = 0.f;
#pragma unroll
        for (int kk = 0; kk < 32; ++kk) {
          float4 rv = rp4[kk];
          ax = fmaf(w1f[4*kk+0], rv.x, ax);
          ay = fmaf(w1f[4*kk+1], rv.y, ay);
          az = fmaf(w1f[4*kk+2], rv.z, az);
          aw = fmaf(w1f[4*kk+3], rv.w, aw);
        }
        part[(q*8 + c)*NH + j] = (ax + ay) + (az + aw);
      }
    }
    __syncthreads();
    int pp = ct*8 + wv;
    if (pp < np) {
      float inR = invl[pp + 1], inL = invl[pp];
      float pr0 = part[(0*8+wv)*NH + lane]      + part[(1*8+wv)*NH + lane];
      float pl0 = part[(2*8+wv)*NH + lane]      + part[(3*8+wv)*NH + lane];
      float pr1 = part[(0*8+wv)*NH + lane + 64] + part[(1*8+wv)*NH + lane + 64];
      float pl1 = part[(2*8+wv)*NH + lane + 64] + part[(3*8+wv)*NH + lane + 64];
      float h0 = fmaf(inR, pr0, fmaf(inL, pl0, b1s[lane]));
      float h1 = fmaf(inR, pr1, fmaf(inL, pl1, b1s[lane + 64]));
      h0 = fmaxf(h0, 0.f); h1 = fmaxf(h1, 0.f);
      float v = w2s[lane]*h0 + w2s[lane + 64]*h1;
#pragma unroll
      for (int off = 32; off; off >>= 1) v += __shfl_down(v, off);
      if (lane == 0) ws[WS_LOG + b*48 + p0 + pp] = v;
    }
    __syncthreads();
  }
}

// ---------------- K3: greedy merge scan, one block per batch, 512 threads ----------------
__global__ __launch_bounds__(512, 1) void k_tree(const int* __restrict__ lengths,
                                                 float* __restrict__ ws,
                                                 const float* __restrict__ w1g,
                                                 const float* __restrict__ b1g,
                                                 const float* __restrict__ w2g,
                                                 float* __restrict__ out) {
  __shared__ float rows[NL*ND];      // 48 KB, slot-reuse on merge (merged row -> left child slot)
  __shared__ float part[8*NH];       // 4 KB
  __shared__ float logits[48];
  __shared__ int physIdx[48];
  __shared__ int lbA[48];
  __shared__ int rbA[48];
  __shared__ float invn[48];
  __shared__ float b1s[NH];
  __shared__ float w2s[NH];
  __shared__ float red[8];
  __shared__ int s_idx, s_rL;
  __shared__ float s_tp, s_max;

  int b = blockIdx.x;
  int t = threadIdx.x;
  int lane = t & 63, wv = t >> 6;
  int j = t & 127, q = t >> 7;
  int len = lengths[b];

  // w1 slice pinned in registers: 128 VGPR, opaque to the optimizer
  float w1f[128];
  {
    const float4* wsrc = (const float4*)(w1g + (size_t)j*512 + q*128);
#pragma unroll
    for (int kk = 0; kk < 32; ++kk) {
      float4 v = wsrc[kk];
      w1f[4*kk+0] = v.x; w1f[4*kk+1] = v.y; w1f[4*kk+2] = v.z; w1f[4*kk+3] = v.w;
    }
  }
#pragma unroll
  for (int kk = 0; kk < 32; ++kk)
    asm volatile("" : "+v"(w1f[4*kk+0]), "+v"(w1f[4*kk+1]), "+v"(w1f[4*kk+2]), "+v"(w1f[4*kk+3]));

  if (t < NH) { b1s[t] = b1g[t]; w2s[t] = w2g[t]; }
  if (t < 48) { physIdx[t] = t; lbA[t] = t; rbA[t] = t; invn[t] = ws[WS_INVN + b*48 + t]; }
  if (t < 47) logits[t] = ws[WS_LOG + b*48 + t];
  {
    const float4* pg4 = (const float4*)(ws + WS_PHYS + (size_t)b*PB_STRIDE);
    float4* rows4 = (float4*)rows;
    for (int u = t; u < NL*64; u += 512) rows4[u] = pg4[u];
  }
  __syncthreads();

  int pidx = -1;
  for (int i = 0; i < NS; ++i) {
    int valid = len - 1 - i; if (valid < 0) valid = 0;
    // ---- R1: deferred invn update for previous merged slot (overlaps GEMV) ----
    if (i > 0 && t == 0)
      invn[s_rL] = 1.0f / (sqrtf(red[4]+red[5]+red[6]+red[7]) + EPSF);
    if (valid >= 2) {
      if (i > 0) {
        // fresh logits for {pidx-1, pidx} clipped to domain (scalar pos regs, no dyn indexing)
        int pos0 = -1, pos1 = -1, np = 0;
        if (pidx > 0) { pos0 = pidx - 1; np = 1; }
        if (pidx <= valid - 1) { if (np) pos1 = pidx; else pos0 = pidx; ++np; }
        {
          int r = (q < 2) ? physIdx[pos0 + 1] : physIdx[pos0];
          const float4* rp4 = (const float4*)(rows + r*ND + (q & 1)*128);
          float ax = 0.f, ay = 0.f, az = 0.f, aw = 0.f;
#pragma unroll
          for (int kk = 0; kk < 32; ++kk) {
            float4 rv = rp4[kk];
            ax = fmaf(w1f[4*kk+0], rv.x, ax);
            ay = fmaf(w1f[4*kk+1], rv.y, ay);
            az = fmaf(w1f[4*kk+2], rv.z, az);
            aw = fmaf(w1f[4*kk+3], rv.w, aw);
          }
          part[(q*2 + 0)*NH + j] = (ax + ay) + (az + aw);
        }
        if (np > 1) {
          int r = (q < 2) ? physIdx[pos1 + 1] : physIdx[pos1];
          const float4* rp4 = (const float4*)(rows + r*ND + (q & 1)*128);
          float ax = 0.f, ay = 0.f, az = 0.f, aw = 0.f;
#pragma unroll
          for (int kk = 0; kk < 32; ++kk) {
            float4 rv = rp4[kk];
            ax = fmaf(w1f[4*kk+0], rv.x, ax);
            ay = fmaf(w1f[4*kk+1], rv.y, ay);
            az = fmaf(w1f[4*kk+2], rv.z, az);
            aw = fmaf(w1f[4*kk+3], rv.w, aw);
          }
          part[(q*2 + 1)*NH + j] = (ax + ay) + (az + aw);
        }
        __syncthreads();                       // B1
        if (wv < np) {
          int p = (wv == 0) ? pos0 : pos1;
          int rR = physIdx[p + 1], rLL = physIdx[p];
          float inR = invn[rR], inL = invn[rLL];
          float pr0 = part[(0*2+wv)*NH + lane]      + part[(1*2+wv)*NH + lane];
          float pl0 = part[(2*2+wv)*NH + lane]      + part[(3*2+wv)*NH + lane];
          float pr1 = part[(0*2+wv)*NH + lane + 64] + part[(1*2+wv)*NH + lane + 64];
          float pl1 = part[(2*2+wv)*NH + lane + 64] + part[(3*2+wv)*NH + lane + 64];
          float h0 = fmaf(inR, pr0, fmaf(inL, pl0, b1s[lane]));
          float h1 = fmaf(inR, pr1, fmaf(inL, pl1, b1s[lane + 64]));
          h0 = fmaxf(h0, 0.f); h1 = fmaxf(h1, 0.f);
          float v = w2s[lane]*h0 + w2s[lane + 64]*h1;
#pragma unroll
          for (int off = 32; off; off >>= 1) v += __shfl_down(v, off);
          if (lane == 0) logits[p] = v;
        }
        __syncthreads();                       // B2
      }
      // ---- R3: argmax (first occurrence) over domain, wave 0 ----
      if (wv == 0) {
        float v = (lane < valid) ? logits[lane] : -INFINITY;
        int bi = lane;
#pragma unroll
        for (int off = 32; off; off >>= 1) {
          float ov = __shfl_down(v, off);
          int  oi = __shfl_down(bi, off);
          if (ov > v || (ov == v && oi < bi)) { v = ov; bi = oi; }
        }
        if (lane == 0) { s_idx = bi; s_max = v; }
      }
    } else {
      // valid==1: idx=0, tp=1. valid==0: all logits bitwise -1e10 -> uniform: idx=0, tp=1/47.
      if (t == 0) { s_idx = 0; s_tp = (valid == 1) ? 1.0f : (1.0f/47.0f); }
    }
    __syncthreads();                           // B3
    int idx = s_idx;
    // ---- R4: merge gather (waves 0-3) || softmax sum (wave 4) || pre-reads (wave 5) ----
    int rL = 0, rR = 0; float slv = 0.f, srv = 0.f, inL = 0.f, inR = 0.f, sumv = 0.f;
    if (t < ND) {
      rL = physIdx[idx]; rR = physIdx[idx + 1];
      slv = rows[rL*ND + t]; srv = rows[rR*ND + t];
      inL = invn[rL]; inR = invn[rR];
      sumv = slv + srv;
      float q2 = sumv * sumv;
#pragma unroll
      for (int off = 32; off; off >>= 1) q2 += __shfl_down(q2, off);
      if (lane == 0) red[wv] = q2;
    }
    int sp0 = 0, sp1 = 0;
    if (t == 0) { s_rL = rL; sp0 = lbA[idx]; sp1 = rbA[idx + 1]; }
    if (wv == 4 && valid >= 2) {
      float ee = (lane < valid) ? expf(logits[lane] - s_max) : 0.f;
#pragma unroll
      for (int off = 32; off; off >>= 1) ee += __shfl_down(ee, off);
      if (lane == 0) s_tp = 1.0f / ee;
    }
    int tt = t - 320;
    int pv = 0, lv = 0, rv_ = 0; float gv = 0.f;
    if (wv == 5 && tt < 47) { pv = physIdx[tt+1]; lv = lbA[tt+1]; rv_ = rbA[tt+1]; gv = logits[tt+1]; }
    __syncthreads();                           // B4
    // ---- R5: outputs, row update, bookkeeping shifts ----
    float undone = valid > 0 ? 1.0f : 0.0f;
    if (t < ND) {
      float invns = 1.0f / (sqrtf(red[0]+red[1]+red[2]+red[3]) + EPSF);
      float featv = sumv * invns;
      int ob = (i*NB + b)*ND + t;
      out[O_FEAT  + ob] = featv * undone;
      out[O_LEFT  + ob] = slv * inL * undone;
      out[O_RIGHT + ob] = srv * inR * undone;
      rows[rL*ND + t] = featv;
      float q3 = featv * featv;
#pragma unroll
      for (int off = 32; off; off >>= 1) q3 += __shfl_down(q3, off);
      if (lane == 0) red[4 + wv] = q3;
    }
    if (t == 0) {
      out[O_TIDX + i*NB + b] = (float)idx;
      out[O_TP   + i*NB + b] = s_tp;
      out[O_SPAN + (i*NB + b)*2 + 0] = (float)sp0;
      out[O_SPAN + (i*NB + b)*2 + 1] = (float)sp1;
    }
    if (wv == 5 && tt < 47) {
      if (tt > idx) { physIdx[tt] = pv; lbA[tt] = lv; logits[tt] = gv; }
      if (tt >= idx) rbA[tt] = rv_;
    }
    __syncthreads();                           // B5
    pidx = idx;
  }
}

extern "C" void kernel_launch(void* const* d_in, const int* in_sizes, int n_in,
                              void* d_out, int out_size, void* d_ws, size_t ws_size,
                              hipStream_t stream) {
  const float* x      = (const float*)d_in[0];
  const int*   lengths= (const int*)  d_in[1];
  const float* amask  = (const float*)d_in[2];
  const float* w_sem  = (const float*)d_in[3];
  const float* w1     = (const float*)d_in[4];
  const float* b1     = (const float*)d_in[5];
  const float* w2     = (const float*)d_in[6];
  float* out = (float*)d_out;
  float* ws  = (float*)d_ws;

  k_transpose<<<dim3(256), dim3(256), 0, stream>>>(w_sem, ws);
  k_sem0<<<dim3(NB*NL), dim3(128), 0, stream>>>(x, lengths, amask, ws, out);
  k_prelogits<<<dim3(256), dim3(512), 0, stream>>>(ws, w1, b1, w2);
  k_tree<<<dim3(NB), dim3(512), 0, stream>>>(lengths, ws, w1, b1, w2, out);
}